// Round 3
// baseline (2522.922 us; speedup 1.0000x reference)
//
#include <hip/hip_runtime.h>

// ---------------------------------------------------------------------------
// VQ-VAE encoder: 4x [conv k=4 s=2 p=1 + ReLU] then nearest-codebook lookup.
// Round 3: (1) VQ 8q x 8c register tile, wave-id = q-group (zt reads are pure
// broadcast, cl reads conflict-free), 512-block grid = 1 full residency round,
// intra-wave shfl lex reduce. LDS intensity 4 fma/float -> VALU-bound.
// (2) conv4 split-K over ci (4x64) for 1024 blocks + deterministic reduce.
// conv1-3 bitwise unchanged; VQ distances bitwise unchanged.
// ---------------------------------------------------------------------------

#define THREADS 256

// Tiled direct conv, NCHW/OIHW, k=4, stride=2, pad=1, fused bias+ReLU.
// CINR = channels processed by this launch slice, CTOT = channel stride of x.
// PARTIAL: acc starts at 0 (no bias), raw store to y + blockIdx.y*plane.
template<int CINR, int KC, int CTOT, bool PARTIAL>
__global__ __launch_bounds__(THREADS)
void conv_tiled_kernel(const float* __restrict__ x, const float* __restrict__ w,
                       const float* __restrict__ bias, float* __restrict__ y,
                       int B, int Cout, int Hin, int Win,
                       int nCt, int nHt, int nWt) {
    constexpr int TH = 8, TW = 16, TC = 64;
    constexpr int XR = 2 * TH + 2;      // 18 input rows per tile
    constexpr int XC = 2 * TW + 2;      // 34 real input cols
    constexpr int ROWP = 36;            // padded row (144B, 16B-aligned)
    constexpr int XTOT = KC * XR * ROWP;
    constexpr int WTOT = TC * KC * 16;

    __shared__ float xs[KC][XR][ROWP];  // staged input patch
    __shared__ float ws[TC][KC][16];    // staged weight slice

    const int Ho = Hin >> 1, Wo = Win >> 1;

    int id = blockIdx.x;
    const int wt = id % nWt; id /= nWt;
    const int ht = id % nHt; id /= nHt;
    const int ct = id % nCt; const int b = id / nCt;
    const int cib = blockIdx.y * CINR;  // ci base of this split

    const int oh0 = ht * TH, ow0 = wt * TW, co0 = ct * TC;
    const int h0 = 2 * oh0 - 1;         // input row of patch row 0
    const int w0 = 2 * ow0 - 1;         // input col of patch col 0

    const int tid  = threadIdx.x;
    const int co_l = (tid >> 4) * 4;    // 16 groups of 4 channels
    const int sp   = tid & 15;
    const int lho  = sp >> 1;           // 0..7
    const int lwo  = (sp & 1) * 8;      // 0 or 8

    float acc[4][8];
    #pragma unroll
    for (int co = 0; co < 4; ++co) {
        const float bv = PARTIAL ? 0.0f : bias[co0 + co_l + co];
        #pragma unroll
        for (int j = 0; j < 8; ++j) acc[co][j] = bv;
    }

    float* __restrict__ xs_f = &xs[0][0][0];
    float* __restrict__ ws_f = &ws[0][0][0];

    for (int cc = 0; cc < CINR / KC; ++cc) {
        const int ci0 = cc * KC;

        // ---- stage input patch (zero-filled borders), coalesced rows ----
        for (int j = tid; j < XTOT; j += THREADS) {
            const int ci = j / (XR * ROWP);
            const int rr = (j - ci * (XR * ROWP)) / ROWP;
            const int c  = j % ROWP;
            const int hi = h0 + rr;
            const int wi = w0 + c;
            float v = 0.0f;
            if (c < XC && (unsigned)hi < (unsigned)Hin && (unsigned)wi < (unsigned)Win)
                v = x[((b * CTOT + cib + ci0 + ci) * Hin + hi) * Win + wi];
            xs_f[j] = v;
        }
        // ---- stage weight slice ----
        for (int j = tid; j < WTOT; j += THREADS) {
            const int co  = j / (KC * 16);
            const int rem = j - co * (KC * 16);
            ws_f[j] = w[((co0 + co) * CTOT + cib + ci0) * 16 + rem];
        }
        __syncthreads();

        // ---- compute: 512 fma per ci per thread ----
        #pragma unroll 1
        for (int ci = 0; ci < KC; ++ci) {
            #pragma unroll
            for (int kh = 0; kh < 4; ++kh) {
                const float* __restrict__ xr = &xs[ci][2 * lho + kh][2 * lwo];
                const float4 a0 = *(const float4*)(xr + 0);
                const float4 a1 = *(const float4*)(xr + 4);
                const float4 a2 = *(const float4*)(xr + 8);
                const float4 a3 = *(const float4*)(xr + 12);
                const float4 a4 = *(const float4*)(xr + 16);
                const float xf[20] = {a0.x, a0.y, a0.z, a0.w,
                                      a1.x, a1.y, a1.z, a1.w,
                                      a2.x, a2.y, a2.z, a2.w,
                                      a3.x, a3.y, a3.z, a3.w,
                                      a4.x, a4.y, a4.z, a4.w};
                #pragma unroll
                for (int co = 0; co < 4; ++co) {
                    const float4 wv = *(const float4*)&ws[co_l + co][ci][kh * 4];
                    #pragma unroll
                    for (int j = 0; j < 8; ++j) {
                        acc[co][j] = fmaf(xf[2 * j + 0], wv.x, acc[co][j]);
                        acc[co][j] = fmaf(xf[2 * j + 1], wv.y, acc[co][j]);
                        acc[co][j] = fmaf(xf[2 * j + 2], wv.z, acc[co][j]);
                        acc[co][j] = fmaf(xf[2 * j + 3], wv.w, acc[co][j]);
                    }
                }
            }
        }
        __syncthreads();
    }

    // ---- epilogue ----
    float* __restrict__ yb = y;
    if (PARTIAL) yb += (size_t)blockIdx.y * (size_t)(B * Cout * Ho * Wo);
    #pragma unroll
    for (int co = 0; co < 4; ++co) {
        float* __restrict__ yp =
            &yb[((b * Cout + co0 + co_l + co) * Ho + oh0 + lho) * Wo + ow0 + lwo];
        float4 r0, r1;
        if (PARTIAL) {
            r0 = make_float4(acc[co][0], acc[co][1], acc[co][2], acc[co][3]);
            r1 = make_float4(acc[co][4], acc[co][5], acc[co][6], acc[co][7]);
        } else {
            r0 = make_float4(fmaxf(acc[co][0], 0.0f), fmaxf(acc[co][1], 0.0f),
                             fmaxf(acc[co][2], 0.0f), fmaxf(acc[co][3], 0.0f));
            r1 = make_float4(fmaxf(acc[co][4], 0.0f), fmaxf(acc[co][5], 0.0f),
                             fmaxf(acc[co][6], 0.0f), fmaxf(acc[co][7], 0.0f));
        }
        *(float4*)yp       = r0;
        *(float4*)(yp + 4) = r1;
    }
}

// conv4 split-K reduce: y = relu(p0+p1+p2+p3 + bias)
__global__ __launch_bounds__(THREADS)
void conv4_reduce_kernel(const float* __restrict__ zp, const float* __restrict__ bias,
                         float* __restrict__ y) {
    const int PLANE = 32 * 256 * 16 * 16;
    int i = blockIdx.x * THREADS + threadIdx.x;
    float s = zp[i];
    s += zp[i + PLANE];
    s += zp[i + 2 * PLANE];
    s += zp[i + 3 * PLANE];
    s += bias[(i >> 8) & 255];
    y[i] = fmaxf(s, 0.0f);
}

// codebook row squared norms
__global__ __launch_bounds__(THREADS)
void cnorm_kernel(const float* __restrict__ cb, float* __restrict__ cn) {
    int c = blockIdx.x * THREADS + threadIdx.x;   // 8192 rows
    const float* __restrict__ row = cb + c * 256;
    float s = 0.0f;
    for (int k = 0; k < 256; k += 4) {
        float4 v = *(const float4*)(row + k);
        s = fmaf(v.x, v.x, s);
        s = fmaf(v.y, v.y, s);
        s = fmaf(v.z, v.z, s);
        s = fmaf(v.w, v.w, s);
    }
    cn[c] = s;
}

__global__ __launch_bounds__(THREADS)
void vq_init_kernel(unsigned long long* __restrict__ packed) {
    int i = blockIdx.x * THREADS + threadIdx.x;
    packed[i] = 0xFFFFFFFFFFFFFFFFULL;
}

// ---------------------------------------------------------------------------
// VQ argmin, 8q x 8c register tile.
// Grid: 256 q-blocks (32 q) x 2 code-splits (4096 codes) = 512 blocks
//       = exactly 2 blocks/CU x 256 CU (single residency round).
// Wave w owns queries qg=w (8 q): zt reads are wave-uniform -> broadcast.
// Lane l owns codes {cb0 + j*64 + l}: cl reads hit 64 distinct rows,
// row stride 20 floats (5 float4, odd) -> conflict-free.
// Per k4: 16 LDS float4 reads feed 256 fma = 4 fma/float (LDS at ~62% while
// VALU saturates). k-ascending acc chains -> distances bitwise identical to
// the previous passing kernel -> identical argmin.
// ---------------------------------------------------------------------------
#define VQ_KCH 16
#define VQ_CTILE 512
__global__ __launch_bounds__(THREADS)
void vq_argmin_kernel(const float* __restrict__ z, const float* __restrict__ cb,
                      const float* __restrict__ cnorm,
                      unsigned long long* __restrict__ packed) {
    __shared__ float zt[256][32];               // 32 KB
    __shared__ float cl[VQ_CTILE][VQ_KCH + 4];  // 512 x 20 floats = 40 KB

    const int t    = threadIdx.x;
    const int lane = t & 63;
    const int qg   = t >> 6;            // wave id = q-octet
    const int qblk   = blockIdx.x >> 1;
    const int csplit = blockIdx.x & 1;
    const int q0  = qblk * 32;
    const int b   = q0 >> 8;
    const int hw0 = q0 & 255;

    // ---- stage zt[k][q] (coalesced float4); first barrier below covers it ----
    {
        const float* __restrict__ zb = z + (b * 256) * 256 + hw0;
        #pragma unroll
        for (int i = 0; i < 8; ++i) {
            const int u = t + i * 256;          // 0..2047 float4 units
            const int k = u >> 3;
            const int m = u & 7;
            *(float4*)&zt[k][m * 4] = *(const float4*)(zb + k * 256 + m * 4);
        }
    }

    float bd[8];
    int   bi[8];
    #pragma unroll
    for (int iq = 0; iq < 8; ++iq) { bd[iq] = 3.4e38f; bi[iq] = 0; }

    const int cbase = csplit * 4096;

    #pragma unroll 1
    for (int ct = 0; ct < 4096 / VQ_CTILE; ++ct) {      // 8 tiles
        const int cb0 = cbase + ct * VQ_CTILE;

        float acc[8][8];
        #pragma unroll
        for (int iq = 0; iq < 8; ++iq)
            #pragma unroll
            for (int j = 0; j < 8; ++j) acc[iq][j] = 0.0f;

        #pragma unroll 1
        for (int kc = 0; kc < 256 / VQ_KCH; ++kc) {     // 16 chunks
            __syncthreads();    // protect prev cl reads (and zt on first pass)
            // stage cl[c][0..15]: 512 rows x 64B, coalesced
            #pragma unroll
            for (int i = 0; i < 8; ++i) {
                const int u = t + i * 256;              // 0..2047 float4 units
                const int c = u >> 2;
                const int m = u & 3;
                *(float4*)&cl[c][m * 4] =
                    *(const float4*)(cb + (cb0 + c) * 256 + kc * VQ_KCH + m * 4);
            }
            __syncthreads();

            const int kb = kc * VQ_KCH;
            #pragma unroll
            for (int k4 = 0; k4 < VQ_KCH / 4; ++k4) {   // 4
                const int kk = kb + k4 * 4;
                float4 za[4], zb4[4];
                #pragma unroll
                for (int kd = 0; kd < 4; ++kd) {
                    za[kd]  = *(const float4*)&zt[kk + kd][qg * 8];
                    zb4[kd] = *(const float4*)&zt[kk + kd][qg * 8 + 4];
                }
                #pragma unroll
                for (int j = 0; j < 8; ++j) {
                    const float4 cv = *(const float4*)&cl[j * 64 + lane][k4 * 4];
                    #pragma unroll
                    for (int kd = 0; kd < 4; ++kd) {
                        const float ck = (kd == 0) ? cv.x : (kd == 1) ? cv.y
                                       : (kd == 2) ? cv.z : cv.w;
                        acc[0][j] = fmaf(za[kd].x,  ck, acc[0][j]);
                        acc[1][j] = fmaf(za[kd].y,  ck, acc[1][j]);
                        acc[2][j] = fmaf(za[kd].z,  ck, acc[2][j]);
                        acc[3][j] = fmaf(za[kd].w,  ck, acc[3][j]);
                        acc[4][j] = fmaf(zb4[kd].x, ck, acc[4][j]);
                        acc[5][j] = fmaf(zb4[kd].y, ck, acc[5][j]);
                        acc[6][j] = fmaf(zb4[kd].z, ck, acc[6][j]);
                        acc[7][j] = fmaf(zb4[kd].w, ck, acc[7][j]);
                    }
                }
            }
        }

        // ---- d = ||c||^2 - 2 z.c ; running lexicographic min ----
        #pragma unroll
        for (int j = 0; j < 8; ++j) {
            const int c = cb0 + j * 64 + lane;
            const float cn = cnorm[c];
            #pragma unroll
            for (int iq = 0; iq < 8; ++iq) {
                const float d = fmaf(-2.0f, acc[iq][j], cn);
                if (d < bd[iq]) { bd[iq] = d; bi[iq] = c; }
            }
        }
    }

    // ---- intra-wave lexicographic (d, idx) reduce over 64 lanes ----
    #pragma unroll
    for (int off = 1; off < 64; off <<= 1) {
        #pragma unroll
        for (int iq = 0; iq < 8; ++iq) {
            const float od = __shfl_xor(bd[iq], off);
            const int   oi = __shfl_xor(bi[iq], off);
            if (od < bd[iq] || (od == bd[iq] && oi < bi[iq])) {
                bd[iq] = od; bi[iq] = oi;
            }
        }
    }
    if (lane == 0) {
        #pragma unroll
        for (int iq = 0; iq < 8; ++iq) {
            unsigned int k = __float_as_uint(bd[iq]);
            k = (k & 0x80000000u) ? ~k : (k | 0x80000000u);
            const unsigned long long pk =
                ((unsigned long long)k << 32) | (unsigned int)bi[iq];
            atomicMin(&packed[q0 + qg * 8 + iq], pk);
        }
    }
}

// Epilogue: out[0:2097152] = codebook[idx] in NCHW; out[2097152:] = (float)idx.
__global__ __launch_bounds__(THREADS)
void gather_kernel(const float* __restrict__ cb,
                   const unsigned long long* __restrict__ packed,
                   float* __restrict__ out) {
    int i = blockIdx.x * THREADS + threadIdx.x;
    if (i < 32 * 256 * 16 * 16) {
        int w = i & 15;
        int h = (i >> 4) & 15;
        int c = (i >> 8) & 255;
        int b = i >> 16;
        int n = (b << 8) | (h << 4) | w;
        int idx = (int)(packed[n] & 0xFFFFFFFFULL);
        out[i] = cb[idx * 256 + c];
    }
    if (i < 8192) {
        int idx = (int)(packed[i] & 0xFFFFFFFFULL);
        out[32 * 256 * 16 * 16 + i] = (float)idx;
    }
}

extern "C" void kernel_launch(void* const* d_in, const int* in_sizes, int n_in,
                              void* d_out, int out_size, void* d_ws, size_t ws_size,
                              hipStream_t stream) {
    const float* x  = (const float*)d_in[0];
    const float* w1 = (const float*)d_in[1];
    const float* b1 = (const float*)d_in[2];
    const float* w2 = (const float*)d_in[3];
    const float* b2 = (const float*)d_in[4];
    const float* w3 = (const float*)d_in[5];
    const float* b3 = (const float*)d_in[6];
    const float* w4 = (const float*)d_in[7];
    const float* b4 = (const float*)d_in[8];
    const float* cb = (const float*)d_in[9];
    float* out = (float*)d_out;

    char* ws = (char*)d_ws;
    // z1: 32*64*128*128 f32 = 134217728 B @ 0           (dead after conv2)
    // z2: 32*128*64*64  f32 =  67108864 B @ 134217728   (dead after conv3)
    // z3: 32*256*32*32  f32 =  33554432 B @ 0           (reuse z1; dead after conv4p)
    // zp: 4 * 8388608 B = 33554432 B     @ 33554432     (inside old z1, after z3)
    // z4: 32*256*16*16  f32 =   8388608 B @ 134217728   (reuse z2)
    // cnorm: 8192 f32 @ 142606336
    // packed: 8192 u64 @ 0 (z3/zp region dead once vq_init runs)
    float* z1 = (float*)(ws);
    float* z2 = (float*)(ws + 134217728);
    float* z3 = (float*)(ws);
    float* zp = (float*)(ws + 33554432);
    float* z4 = (float*)(ws + 134217728);
    float* cn = (float*)(ws + 142606336);
    unsigned long long* pk = (unsigned long long*)(ws);

    // conv1: (32,3,256,256) -> (32,64,128,128)   grid: 32 * 1ct * 16ht * 8wt
    conv_tiled_kernel<3, 3, 3, false><<<32 * 1 * 16 * 8, THREADS, 0, stream>>>(
        x, w1, b1, z1, 32, 64, 256, 256, 1, 16, 8);
    // conv2: -> (32,128,64,64)                   grid: 32 * 2 * 8 * 4
    conv_tiled_kernel<64, 4, 64, false><<<32 * 2 * 8 * 4, THREADS, 0, stream>>>(
        z1, w2, b2, z2, 32, 128, 128, 128, 2, 8, 4);
    // conv3: -> (32,256,32,32)                   grid: 32 * 4 * 4 * 2
    conv_tiled_kernel<128, 4, 128, false><<<32 * 4 * 4 * 2, THREADS, 0, stream>>>(
        z2, w3, b3, z3, 32, 256, 64, 64, 4, 4, 2);
    // conv4 split-K: 4 splits of 64 ci -> partials, then reduce
    conv_tiled_kernel<64, 4, 256, true><<<dim3(32 * 4 * 2 * 1, 4), THREADS, 0, stream>>>(
        z3, w4, b4, zp, 32, 256, 32, 32, 4, 2, 1);
    conv4_reduce_kernel<<<(32 * 256 * 16 * 16) / THREADS, THREADS, 0, stream>>>(
        zp, b4, z4);

    // VQ
    cnorm_kernel<<<8192 / THREADS, THREADS, 0, stream>>>(cb, cn);
    vq_init_kernel<<<8192 / THREADS, THREADS, 0, stream>>>(pk);
    vq_argmin_kernel<<<256 * 2, THREADS, 0, stream>>>(z4, cb, cn, pk);

    // epilogue
    gather_kernel<<<(32 * 256 * 16 * 16) / THREADS, THREADS, 0, stream>>>(cb, pk, out);
}

// Round 4
// 2024.770 us; speedup vs baseline: 1.2460x; 1.2460x over previous
//
#include <hip/hip_runtime.h>

// ---------------------------------------------------------------------------
// VQ-VAE encoder: 4x [conv k=4 s=2 p=1 + ReLU] then nearest-codebook lookup.
// Round 4: VQ back to 4q x 8c tile but with codebook tile stored TRANSPOSED
// in LDS (cl[k][c]) so both operand reads are contiguous broadcast groups
// (1-2 cy, no 4/8-way conflicts). LDS exactly 40 KB -> 4 blocks/CU, grid
// 1024 = one full residency round. Reduce scratch aliased into dead zt.
// conv path unchanged from round 3 (split-K conv4 kept: it won ~225us).
// Distances bitwise identical to previous passing rounds.
// ---------------------------------------------------------------------------

#define THREADS 256

// Tiled direct conv, NCHW/OIHW, k=4, stride=2, pad=1, fused bias+ReLU.
// CINR = channels processed by this launch slice, CTOT = channel stride of x.
// PARTIAL: acc starts at 0 (no bias), raw store to y + blockIdx.y*plane.
template<int CINR, int KC, int CTOT, bool PARTIAL>
__global__ __launch_bounds__(THREADS)
void conv_tiled_kernel(const float* __restrict__ x, const float* __restrict__ w,
                       const float* __restrict__ bias, float* __restrict__ y,
                       int B, int Cout, int Hin, int Win,
                       int nCt, int nHt, int nWt) {
    constexpr int TH = 8, TW = 16, TC = 64;
    constexpr int XR = 2 * TH + 2;      // 18 input rows per tile
    constexpr int XC = 2 * TW + 2;      // 34 real input cols
    constexpr int ROWP = 36;            // padded row (144B, 16B-aligned)
    constexpr int XTOT = KC * XR * ROWP;
    constexpr int WTOT = TC * KC * 16;

    __shared__ float xs[KC][XR][ROWP];  // staged input patch
    __shared__ float ws[TC][KC][16];    // staged weight slice

    const int Ho = Hin >> 1, Wo = Win >> 1;

    int id = blockIdx.x;
    const int wt = id % nWt; id /= nWt;
    const int ht = id % nHt; id /= nHt;
    const int ct = id % nCt; const int b = id / nCt;
    const int cib = blockIdx.y * CINR;  // ci base of this split

    const int oh0 = ht * TH, ow0 = wt * TW, co0 = ct * TC;
    const int h0 = 2 * oh0 - 1;         // input row of patch row 0
    const int w0 = 2 * ow0 - 1;         // input col of patch col 0

    const int tid  = threadIdx.x;
    const int co_l = (tid >> 4) * 4;    // 16 groups of 4 channels
    const int sp   = tid & 15;
    const int lho  = sp >> 1;           // 0..7
    const int lwo  = (sp & 1) * 8;      // 0 or 8

    float acc[4][8];
    #pragma unroll
    for (int co = 0; co < 4; ++co) {
        const float bv = PARTIAL ? 0.0f : bias[co0 + co_l + co];
        #pragma unroll
        for (int j = 0; j < 8; ++j) acc[co][j] = bv;
    }

    float* __restrict__ xs_f = &xs[0][0][0];
    float* __restrict__ ws_f = &ws[0][0][0];

    for (int cc = 0; cc < CINR / KC; ++cc) {
        const int ci0 = cc * KC;

        // ---- stage input patch (zero-filled borders), coalesced rows ----
        for (int j = tid; j < XTOT; j += THREADS) {
            const int ci = j / (XR * ROWP);
            const int rr = (j - ci * (XR * ROWP)) / ROWP;
            const int c  = j % ROWP;
            const int hi = h0 + rr;
            const int wi = w0 + c;
            float v = 0.0f;
            if (c < XC && (unsigned)hi < (unsigned)Hin && (unsigned)wi < (unsigned)Win)
                v = x[((b * CTOT + cib + ci0 + ci) * Hin + hi) * Win + wi];
            xs_f[j] = v;
        }
        // ---- stage weight slice ----
        for (int j = tid; j < WTOT; j += THREADS) {
            const int co  = j / (KC * 16);
            const int rem = j - co * (KC * 16);
            ws_f[j] = w[((co0 + co) * CTOT + cib + ci0) * 16 + rem];
        }
        __syncthreads();

        // ---- compute: 512 fma per ci per thread ----
        #pragma unroll 1
        for (int ci = 0; ci < KC; ++ci) {
            #pragma unroll
            for (int kh = 0; kh < 4; ++kh) {
                const float* __restrict__ xr = &xs[ci][2 * lho + kh][2 * lwo];
                const float4 a0 = *(const float4*)(xr + 0);
                const float4 a1 = *(const float4*)(xr + 4);
                const float4 a2 = *(const float4*)(xr + 8);
                const float4 a3 = *(const float4*)(xr + 12);
                const float4 a4 = *(const float4*)(xr + 16);
                const float xf[20] = {a0.x, a0.y, a0.z, a0.w,
                                      a1.x, a1.y, a1.z, a1.w,
                                      a2.x, a2.y, a2.z, a2.w,
                                      a3.x, a3.y, a3.z, a3.w,
                                      a4.x, a4.y, a4.z, a4.w};
                #pragma unroll
                for (int co = 0; co < 4; ++co) {
                    const float4 wv = *(const float4*)&ws[co_l + co][ci][kh * 4];
                    #pragma unroll
                    for (int j = 0; j < 8; ++j) {
                        acc[co][j] = fmaf(xf[2 * j + 0], wv.x, acc[co][j]);
                        acc[co][j] = fmaf(xf[2 * j + 1], wv.y, acc[co][j]);
                        acc[co][j] = fmaf(xf[2 * j + 2], wv.z, acc[co][j]);
                        acc[co][j] = fmaf(xf[2 * j + 3], wv.w, acc[co][j]);
                    }
                }
            }
        }
        __syncthreads();
    }

    // ---- epilogue ----
    float* __restrict__ yb = y;
    if (PARTIAL) yb += (size_t)blockIdx.y * (size_t)(B * Cout * Ho * Wo);
    #pragma unroll
    for (int co = 0; co < 4; ++co) {
        float* __restrict__ yp =
            &yb[((b * Cout + co0 + co_l + co) * Ho + oh0 + lho) * Wo + ow0 + lwo];
        float4 r0, r1;
        if (PARTIAL) {
            r0 = make_float4(acc[co][0], acc[co][1], acc[co][2], acc[co][3]);
            r1 = make_float4(acc[co][4], acc[co][5], acc[co][6], acc[co][7]);
        } else {
            r0 = make_float4(fmaxf(acc[co][0], 0.0f), fmaxf(acc[co][1], 0.0f),
                             fmaxf(acc[co][2], 0.0f), fmaxf(acc[co][3], 0.0f));
            r1 = make_float4(fmaxf(acc[co][4], 0.0f), fmaxf(acc[co][5], 0.0f),
                             fmaxf(acc[co][6], 0.0f), fmaxf(acc[co][7], 0.0f));
        }
        *(float4*)yp       = r0;
        *(float4*)(yp + 4) = r1;
    }
}

// conv4 split-K reduce: y = relu(p0+p1+p2+p3 + bias)
__global__ __launch_bounds__(THREADS)
void conv4_reduce_kernel(const float* __restrict__ zp, const float* __restrict__ bias,
                         float* __restrict__ y) {
    const int PLANE = 32 * 256 * 16 * 16;
    int i = blockIdx.x * THREADS + threadIdx.x;
    float s = zp[i];
    s += zp[i + PLANE];
    s += zp[i + 2 * PLANE];
    s += zp[i + 3 * PLANE];
    s += bias[(i >> 8) & 255];
    y[i] = fmaxf(s, 0.0f);
}

// codebook row squared norms + init of packed argmin cells (fused)
__global__ __launch_bounds__(THREADS)
void cnorm_kernel(const float* __restrict__ cb, float* __restrict__ cn,
                  unsigned long long* __restrict__ packed) {
    int c = blockIdx.x * THREADS + threadIdx.x;   // 8192 rows
    const float* __restrict__ row = cb + c * 256;
    float s = 0.0f;
    for (int k = 0; k < 256; k += 4) {
        float4 v = *(const float4*)(row + k);
        s = fmaf(v.x, v.x, s);
        s = fmaf(v.y, v.y, s);
        s = fmaf(v.z, v.z, s);
        s = fmaf(v.w, v.w, s);
    }
    cn[c] = s;
    packed[c] = 0xFFFFFFFFFFFFFFFFULL;            // 8192 queries == 8192 codes
}

// ---------------------------------------------------------------------------
// VQ argmin, 4q x 8c register tile, transposed codebook tile in LDS.
// Grid: 256 q-blocks (32 q) x 4 code-splits (2048 codes) = 1024 blocks
//       = exactly 4 blocks/CU x 256 CU (one residency round; LDS = 40 KB).
// Thread t: qg = t&7 (4 q), cg = t>>3 (8 c). Per k:
//   zt[k][qg*4]  -> 8 distinct addrs x 16B = 128B contiguous, 1 cy
//   cl[k][cg*8]  -> 8 distinct addrs, 2-way aliased (free)
//   32 fma. LDS ~31% of peak at VALU=100%.
// k-ascending fmaf chains -> distances bitwise identical -> argmin identical.
// ---------------------------------------------------------------------------
#define VQ_KCH 8
#define VQ_CTILE 256
__global__ __launch_bounds__(THREADS, 4)
void vq_argmin_kernel(const float* __restrict__ z, const float* __restrict__ cb,
                      const float* __restrict__ cnorm,
                      unsigned long long* __restrict__ packed) {
    __shared__ float zt[256][32];               // 32 KB, [k][q]
    __shared__ float cl[VQ_KCH][VQ_CTILE];      //  8 KB, [k][c] (transposed)

    const int t    = threadIdx.x;
    const int lane = t & 63;
    const int wv   = t >> 6;
    const int qg   = t & 7;             // 8 groups x 4 q
    const int cg   = t >> 3;            // 32 groups x 8 c
    const int qblk   = blockIdx.x >> 2;
    const int csplit = blockIdx.x & 3;
    const int q0  = qblk * 32;
    const int b   = q0 >> 8;
    const int hw0 = q0 & 255;

    // ---- stage zt[k][q] (coalesced float4); first barrier below covers it ----
    {
        const float* __restrict__ zb = z + (b * 256) * 256 + hw0;
        #pragma unroll
        for (int i = 0; i < 8; ++i) {
            const int u = t + i * 256;          // 0..2047 float4 units
            const int k = u >> 3;
            const int m = u & 7;
            *(float4*)&zt[k][m * 4] = *(const float4*)(zb + k * 256 + m * 4);
        }
    }

    float bd[4];
    int   bi[4];
    #pragma unroll
    for (int iq = 0; iq < 4; ++iq) { bd[iq] = 3.4e38f; bi[iq] = 0; }

    const int cbase = csplit * 2048;

    #pragma unroll 1
    for (int ct = 0; ct < 2048 / VQ_CTILE; ++ct) {      // 8 tiles
        const int cb0 = cbase + ct * VQ_CTILE;

        float acc[4][8];
        #pragma unroll
        for (int iq = 0; iq < 4; ++iq)
            #pragma unroll
            for (int j = 0; j < 8; ++j) acc[iq][j] = 0.0f;

        #pragma unroll 1
        for (int kc = 0; kc < 256 / VQ_KCH; ++kc) {     // 32 chunks
            __syncthreads();    // protect prev chunk's cl reads (zt on first)
            // stage cl transposed: read row-major float4, write 4 scalars.
            // 256 c x 8 k per chunk; writes are 2-way aliased (free).
            #pragma unroll
            for (int i = 0; i < 2; ++i) {
                const int u = t + i * 256;              // 0..511
                const int c = u >> 1;
                const int m = u & 1;
                const float4 v =
                    *(const float4*)(cb + (cb0 + c) * 256 + kc * VQ_KCH + m * 4);
                cl[m * 4 + 0][c] = v.x;
                cl[m * 4 + 1][c] = v.y;
                cl[m * 4 + 2][c] = v.z;
                cl[m * 4 + 3][c] = v.w;
            }
            __syncthreads();

            const int kb = kc * VQ_KCH;
            #pragma unroll
            for (int kk = 0; kk < VQ_KCH; ++kk) {
                const float4 zv = *(const float4*)&zt[kb + kk][qg * 4];
                const float4 c0 = *(const float4*)&cl[kk][cg * 8];
                const float4 c1 = *(const float4*)&cl[kk][cg * 8 + 4];
                acc[0][0] = fmaf(zv.x, c0.x, acc[0][0]);
                acc[1][0] = fmaf(zv.y, c0.x, acc[1][0]);
                acc[2][0] = fmaf(zv.z, c0.x, acc[2][0]);
                acc[3][0] = fmaf(zv.w, c0.x, acc[3][0]);
                acc[0][1] = fmaf(zv.x, c0.y, acc[0][1]);
                acc[1][1] = fmaf(zv.y, c0.y, acc[1][1]);
                acc[2][1] = fmaf(zv.z, c0.y, acc[2][1]);
                acc[3][1] = fmaf(zv.w, c0.y, acc[3][1]);
                acc[0][2] = fmaf(zv.x, c0.z, acc[0][2]);
                acc[1][2] = fmaf(zv.y, c0.z, acc[1][2]);
                acc[2][2] = fmaf(zv.z, c0.z, acc[2][2]);
                acc[3][2] = fmaf(zv.w, c0.z, acc[3][2]);
                acc[0][3] = fmaf(zv.x, c0.w, acc[0][3]);
                acc[1][3] = fmaf(zv.y, c0.w, acc[1][3]);
                acc[2][3] = fmaf(zv.z, c0.w, acc[2][3]);
                acc[3][3] = fmaf(zv.w, c0.w, acc[3][3]);
                acc[0][4] = fmaf(zv.x, c1.x, acc[0][4]);
                acc[1][4] = fmaf(zv.y, c1.x, acc[1][4]);
                acc[2][4] = fmaf(zv.z, c1.x, acc[2][4]);
                acc[3][4] = fmaf(zv.w, c1.x, acc[3][4]);
                acc[0][5] = fmaf(zv.x, c1.y, acc[0][5]);
                acc[1][5] = fmaf(zv.y, c1.y, acc[1][5]);
                acc[2][5] = fmaf(zv.z, c1.y, acc[2][5]);
                acc[3][5] = fmaf(zv.w, c1.y, acc[3][5]);
                acc[0][6] = fmaf(zv.x, c1.z, acc[0][6]);
                acc[1][6] = fmaf(zv.y, c1.z, acc[1][6]);
                acc[2][6] = fmaf(zv.z, c1.z, acc[2][6]);
                acc[3][6] = fmaf(zv.w, c1.z, acc[3][6]);
                acc[0][7] = fmaf(zv.x, c1.w, acc[0][7]);
                acc[1][7] = fmaf(zv.y, c1.w, acc[1][7]);
                acc[2][7] = fmaf(zv.z, c1.w, acc[2][7]);
                acc[3][7] = fmaf(zv.w, c1.w, acc[3][7]);
            }
        }

        // ---- d = ||c||^2 - 2 z.c ; running lexicographic min (c ascending) ----
        #pragma unroll
        for (int j = 0; j < 8; ++j) {
            const int c = cb0 + cg * 8 + j;
            const float cn = cnorm[c];
            #pragma unroll
            for (int iq = 0; iq < 4; ++iq) {
                const float d = fmaf(-2.0f, acc[iq][j], cn);
                if (d < bd[iq]) { bd[iq] = d; bi[iq] = c; }
            }
        }
    }

    // ---- intra-wave lex reduce over cg bits (lane bits 3..5) ----
    #pragma unroll
    for (int off = 8; off <= 32; off <<= 1) {
        #pragma unroll
        for (int iq = 0; iq < 4; ++iq) {
            const float od = __shfl_xor(bd[iq], off);
            const int   oi = __shfl_xor(bi[iq], off);
            if (od < bd[iq] || (od == bd[iq] && oi < bi[iq])) {
                bd[iq] = od; bi[iq] = oi;
            }
        }
    }

    // ---- cross-wave reduce via scratch aliased into dead zt ----
    __syncthreads();                    // all compute reads of zt/cl done
    float* __restrict__ pd = &zt[0][0];           // [4][8][4] = 128 floats
    int*   __restrict__ pi = (int*)(&zt[0][0] + 128);
    if (lane < 8) {
        #pragma unroll
        for (int iq = 0; iq < 4; ++iq) {
            pd[(wv * 8 + qg) * 4 + iq] = bd[iq];
            pi[(wv * 8 + qg) * 4 + iq] = bi[iq];
        }
    }
    __syncthreads();
    if (t < 32) {
        const int qq = t >> 2;          // qg
        const int iq = t & 3;
        float best = pd[(0 * 8 + qq) * 4 + iq];
        int   besti = pi[(0 * 8 + qq) * 4 + iq];
        #pragma unroll
        for (int w2 = 1; w2 < 4; ++w2) {
            const float d = pd[(w2 * 8 + qq) * 4 + iq];
            const int  i2 = pi[(w2 * 8 + qq) * 4 + iq];
            if (d < best || (d == best && i2 < besti)) { best = d; besti = i2; }
        }
        unsigned int k = __float_as_uint(best);
        k = (k & 0x80000000u) ? ~k : (k | 0x80000000u);
        const unsigned long long pkv =
            ((unsigned long long)k << 32) | (unsigned int)besti;
        atomicMin(&packed[q0 + qq * 4 + iq], pkv);
    }
}

// Epilogue: out[0:2097152] = codebook[idx] in NCHW; out[2097152:] = (float)idx.
__global__ __launch_bounds__(THREADS)
void gather_kernel(const float* __restrict__ cb,
                   const unsigned long long* __restrict__ packed,
                   float* __restrict__ out) {
    int i = blockIdx.x * THREADS + threadIdx.x;
    if (i < 32 * 256 * 16 * 16) {
        int w = i & 15;
        int h = (i >> 4) & 15;
        int c = (i >> 8) & 255;
        int b = i >> 16;
        int n = (b << 8) | (h << 4) | w;
        int idx = (int)(packed[n] & 0xFFFFFFFFULL);
        out[i] = cb[idx * 256 + c];
    }
    if (i < 8192) {
        int idx = (int)(packed[i] & 0xFFFFFFFFULL);
        out[32 * 256 * 16 * 16 + i] = (float)idx;
    }
}

extern "C" void kernel_launch(void* const* d_in, const int* in_sizes, int n_in,
                              void* d_out, int out_size, void* d_ws, size_t ws_size,
                              hipStream_t stream) {
    const float* x  = (const float*)d_in[0];
    const float* w1 = (const float*)d_in[1];
    const float* b1 = (const float*)d_in[2];
    const float* w2 = (const float*)d_in[3];
    const float* b2 = (const float*)d_in[4];
    const float* w3 = (const float*)d_in[5];
    const float* b3 = (const float*)d_in[6];
    const float* w4 = (const float*)d_in[7];
    const float* b4 = (const float*)d_in[8];
    const float* cb = (const float*)d_in[9];
    float* out = (float*)d_out;

    char* ws = (char*)d_ws;
    // z1: 32*64*128*128 f32 = 134217728 B @ 0           (dead after conv2)
    // z2: 32*128*64*64  f32 =  67108864 B @ 134217728   (dead after conv3)
    // z3: 32*256*32*32  f32 =  33554432 B @ 0           (reuse z1; dead after conv4p)
    // zp: 4 * 8388608 B = 33554432 B     @ 33554432     (inside old z1, after z3)
    // z4: 32*256*16*16  f32 =   8388608 B @ 134217728   (reuse z2)
    // cnorm: 8192 f32 @ 142606336
    // packed: 8192 u64 @ 0 (z3/zp region dead once cnorm runs)
    float* z1 = (float*)(ws);
    float* z2 = (float*)(ws + 134217728);
    float* z3 = (float*)(ws);
    float* zp = (float*)(ws + 33554432);
    float* z4 = (float*)(ws + 134217728);
    float* cn = (float*)(ws + 142606336);
    unsigned long long* pk = (unsigned long long*)(ws);

    // conv1: (32,3,256,256) -> (32,64,128,128)   grid: 32 * 1ct * 16ht * 8wt
    conv_tiled_kernel<3, 3, 3, false><<<32 * 1 * 16 * 8, THREADS, 0, stream>>>(
        x, w1, b1, z1, 32, 64, 256, 256, 1, 16, 8);
    // conv2: -> (32,128,64,64)                   grid: 32 * 2 * 8 * 4
    conv_tiled_kernel<64, 4, 64, false><<<32 * 2 * 8 * 4, THREADS, 0, stream>>>(
        z1, w2, b2, z2, 32, 128, 128, 128, 2, 8, 4);
    // conv3: -> (32,256,32,32)                   grid: 32 * 4 * 4 * 2
    conv_tiled_kernel<128, 4, 128, false><<<32 * 4 * 4 * 2, THREADS, 0, stream>>>(
        z2, w3, b3, z3, 32, 256, 64, 64, 4, 4, 2);
    // conv4 split-K: 4 splits of 64 ci -> partials, then reduce
    conv_tiled_kernel<64, 4, 256, true><<<dim3(32 * 4 * 2 * 1, 4), THREADS, 0, stream>>>(
        z3, w4, b4, zp, 32, 256, 32, 32, 4, 2, 1);
    conv4_reduce_kernel<<<(32 * 256 * 16 * 16) / THREADS, THREADS, 0, stream>>>(
        zp, b4, z4);

    // VQ (cnorm fuses the packed-cell init)
    cnorm_kernel<<<8192 / THREADS, THREADS, 0, stream>>>(cb, cn, pk);
    vq_argmin_kernel<<<256 * 4, THREADS, 0, stream>>>(z4, cb, cn, pk);

    // epilogue
    gather_kernel<<<(32 * 256 * 16 * 16) / THREADS, THREADS, 0, stream>>>(cb, pk, out);
}